// Round 5
// baseline (154.874 us; speedup 1.0000x reference)
//
#include <hip/hip_runtime.h>
#include <math.h>

#define DIM 160
#define HT 16
#define ROWS (HT + 6)          // 22 staged rows (h-halo)
#define LROWF 164              // padded tmpL row stride in floats (160 ≡ 0 mod 32 banks)
#define CHUNK 4                // output d-slices per block
#define NSTEP (CHUNK + 6)      // 10 slice steps
#define THREADS 320
#define WITEMS (ROWS * 40)     // 880 W-blur float4 items per slice

struct W7 { float w[7]; };

__device__ __forceinline__ void fma4(float4& a, float w, const float4& v) {
    a.x += w * v.x; a.y += w * v.y; a.z += w * v.z; a.w += w * v.w;
}

__global__ __launch_bounds__(THREADS) void blur3d_fused(
    const float* __restrict__ in, float* __restrict__ out, W7 wt) {
    __shared__ float tmpL[2][ROWS * LROWF];   // 2 x 14.4 KB W-blurred slices

    const int tilesH = DIM / HT;          // 10
    const int nchunk = DIM / CHUNK;       // 40
    const int b   = blockIdx.x;
    const int nc  = b / (tilesH * nchunk);
    const int rem = b % (tilesH * nchunk);
    const int h0  = (rem / nchunk) * HT;
    const int d0  = (rem % nchunk) * CHUNK;
    const int tid = threadIdx.x;

    const float* src = in  + (size_t)nc * (DIM * DIM * DIM);
    float*       dst = out + (size_t)nc * (DIM * DIM * DIM);

    const int g  = tid / 40;   // 0..7 : owns output tile rows 2g, 2g+1
    const int cc = tid % 40;   // float4 column

    const float4 z4 = make_float4(0.f, 0.f, 0.f, 0.f);
    float4 st[3][3];           // in-flight raw loads (3 items x {left,center,right})
    float4 win[7][2];          // 7-slice register ring of WH-blurred values

    // ---- issue raw global loads for slice s (zero outside any range) ----
    auto wload = [&](int s) {
#pragma unroll
        for (int p = 0; p < 3; ++p) { st[p][0] = z4; st[p][1] = z4; st[p][2] = z4; }
        if ((unsigned)s < DIM) {
            const float* sl = src + (size_t)s * (DIM * DIM);
#pragma unroll
            for (int p = 0; p < 3; ++p) {
                int i = tid + p * THREADS;
                if (i < WITEMS) {
                    int r = i / 40, c = i % 40, h = h0 - 3 + r;
                    if ((unsigned)h < DIM) {
                        const float4* row = (const float4*)(sl + h * DIM);
                        st[p][1] = row[c];
                        if (c >= 1)  st[p][0] = row[c - 1];
                        if (c <= 38) st[p][2] = row[c + 1];
                    }
                }
            }
        }
    };
    // ---- W-blur staged regs -> tmpL[buf] (guards already zeroed) ----
    auto wblur = [&](int buf) {
#pragma unroll
        for (int p = 0; p < 3; ++p) {
            int i = tid + p * THREADS;
            if (i < WITEMS) {
                int r = i / 40, c = i % 40;
                float f1 = st[p][0].y, f2 = st[p][0].z, f3 = st[p][0].w;
                float f4 = st[p][1].x, f5 = st[p][1].y, f6 = st[p][1].z, f7 = st[p][1].w;
                float f8 = st[p][2].x, f9 = st[p][2].y, f10 = st[p][2].z;
                float4 o;
                o.x = wt.w[0]*f1 + wt.w[1]*f2 + wt.w[2]*f3 + wt.w[3]*f4
                    + wt.w[4]*f5 + wt.w[5]*f6 + wt.w[6]*f7;
                o.y = wt.w[0]*f2 + wt.w[1]*f3 + wt.w[2]*f4 + wt.w[3]*f5
                    + wt.w[4]*f6 + wt.w[5]*f7 + wt.w[6]*f8;
                o.z = wt.w[0]*f3 + wt.w[1]*f4 + wt.w[2]*f5 + wt.w[3]*f6
                    + wt.w[4]*f7 + wt.w[5]*f8 + wt.w[6]*f9;
                o.w = wt.w[0]*f4 + wt.w[1]*f5 + wt.w[2]*f6 + wt.w[3]*f7
                    + wt.w[4]*f8 + wt.w[5]*f9 + wt.w[6]*f10;
                ((float4*)(tmpL[buf] + r * LROWF))[c] = o;
            }
        }
    };
    // ---- H-blur 2 consecutive rows from tmpL[buf] via 8-read window ----
    auto hblur = [&](int buf, float4* slot) {
        float4 a0 = z4, a1 = z4;
#pragma unroll
        for (int j = 0; j < 8; ++j) {
            float4 t4 = ((const float4*)(tmpL[buf] + (2 * g + j) * LROWF))[cc];
            if (j < 7) fma4(a0, wt.w[j], t4);       // output row 2g
            if (j > 0) fma4(a1, wt.w[j - 1], t4);   // output row 2g+1
        }
        slot[0] = a0; slot[1] = a1;
    };

    // ---- prologue: W-blur first slice (d0-3) into tmpL[0] ----
    wload(d0 - 3);
    wblur(0);
    __syncthreads();

    // ---- main march: fully unrolled -> all ring/buffer indices static ----
#pragma unroll
    for (int t = 0; t < NSTEP; ++t) {
        if (t < NSTEP - 1) wload(d0 - 2 + t);     // issue next slice's loads
        hblur(t & 1, win[t % 7]);                 // consume current slice
        if (t >= 6) {
            const int d = d0 + t - 6;
            float4* obase = (float4*)(dst + (size_t)d * (DIM * DIM));
#pragma unroll
            for (int r2 = 0; r2 < 2; ++r2) {
                float4 o = z4;
#pragma unroll
                for (int j = 0; j < 7; ++j)
                    fma4(o, wt.w[j], win[(t + 1 + j) % 7][r2]);
                obase[(h0 + 2 * g + r2) * 40 + cc] = o;
            }
        }
        if (t < NSTEP - 1) wblur((t + 1) & 1);    // commit next slice
        __syncthreads();
    }
}

extern "C" void kernel_launch(void* const* d_in, const int* in_sizes, int n_in,
                              void* d_out, int out_size, void* d_ws, size_t ws_size,
                              hipStream_t stream) {
    const float* x = (const float*)d_in[0];
    float* out = (float*)d_out;
    const int total = out_size;                      // 2*2*160^3

    W7 wt;
    double s = 0.0;
    for (int i = 0; i < 7; ++i) {
        double v = exp(-((i - 3) * (i - 3)) / 8.0);
        wt.w[i] = (float)v;
        s += v;
    }
    for (int i = 0; i < 7; ++i) wt.w[i] = (float)(wt.w[i] / s);

    const int nc = total / (DIM * DIM * DIM);            // 4
    const int grid = nc * (DIM / HT) * (DIM / CHUNK);    // 4*10*40 = 1600
    blur3d_fused<<<grid, THREADS, 0, stream>>>(x, out, wt);
}

// Round 6
// 85.108 us; speedup vs baseline: 1.8197x; 1.8197x over previous
//
#include <hip/hip_runtime.h>
#include <math.h>

#define DIM 160
#define HT 16
#define WT4 20              // output float4 per row per tile (80 floats)
#define ROWS 22             // h rows incl halo
#define SROW 22             // staged float4 per row (w0-4 .. w0+83)
#define IST 88              // inL row stride (floats)
#define TST 84              // tmpL row stride (floats, banks-friendly)
#define ISL (ROWS * IST)    // 1936 floats per inL buffer
#define TSL (ROWS * TST)    // 1848 floats per tmpL buffer
#define CHUNK 8
#define NSTEP (CHUNK + 6)   // 14
#define THREADS 320
#define NSTAGE (ROWS * SROW)  // 484 staged float4 per slice
#define NWB (ROWS * WT4)      // 440 w-blur items per slice

struct W7 { float w[7]; };

__device__ __forceinline__ void fma4(float4& a, float w, const float4& v) {
    a.x += w * v.x; a.y += w * v.y; a.z += w * v.z; a.w += w * v.w;
}

__global__ __launch_bounds__(THREADS) void blur3d_fused(
    const float4* __restrict__ in, float4* __restrict__ out, W7 wt) {
    __shared__ float inL[2 * ISL];    // raw slices, double-buffered (15.5 KB)
    __shared__ float tmpL[2 * TSL];   // W-blurred slices, double-buffered (14.8 KB)

    const int nchunk = DIM / CHUNK;                    // 20
    const int b   = blockIdx.x;
    const int dc  = b % nchunk;                        // fastest: d-halo L2 locality
    const int wti = (b / nchunk) & 1;
    const int hti = (b / (nchunk * 2)) % (DIM / HT);
    const int nci = b / (nchunk * 2 * (DIM / HT));
    const int h0  = hti * HT;
    const int d0  = dc * CHUNK;

    const float4* src = in  + (size_t)nci * (DIM * DIM * DIM / 4);
    float4*       dst = out + (size_t)nci * (DIM * DIM * DIM / 4);

    const int tid = threadIdx.x;

    // ---- staging geometry (step-invariant) ----
    const int r0s = tid / SROW, k0s = tid % SROW;
    const int i1  = tid + THREADS;
    const int r1s = i1 / SROW, k1s = i1 % SROW;
    const int gk0 = wti * WT4 - 1 + k0s;        // global f4 column (w0/4 - 1 + k)
    const int gk1 = wti * WT4 - 1 + k1s;
    const int hh0 = h0 - 3 + r0s;
    const int hh1 = h0 - 3 + r1s;
    const bool v0ok = ((unsigned)hh0 < DIM) && ((unsigned)gk0 < 40);
    const bool v1ok = (i1 < NSTAGE) && ((unsigned)hh1 < DIM) && ((unsigned)gk1 < 40);
    const int goff0 = hh0 * 40 + gk0;
    const int goff1 = hh1 * 40 + gk1;
    const int loff0 = r0s * IST + 4 * k0s;      // float offsets into inL buffer
    const int loff1 = r1s * IST + 4 * k1s;

    // ---- w-blur geometry ----
    const int rw0 = tid / WT4, cw0 = tid % WT4;
    const int i1w = tid + THREADS;
    const int rw1 = i1w / WT4, cw1 = i1w % WT4;
    const bool w1ok = (i1w < NWB);

    // ---- h-blur / output geometry ----
    const int g  = tid / WT4;     // 0..15 output row in tile
    const int cc = tid % WT4;     // output f4 column in tile
    const int obase = (h0 + g) * 40 + wti * WT4 + cc;

    const float4 z4 = make_float4(0.f, 0.f, 0.f, 0.f);
    float4 ld0, ld1;                       // in-flight staging (named, no arrays)
    float4 r0, r1, r2, r3, r4, r5, r6;     // named 7-slice D ring
    r0 = r1 = r2 = r3 = r4 = r5 = r6 = z4;

    auto sload = [&](int s) {              // issue global loads for abs slice s
        ld0 = z4; ld1 = z4;
        if ((unsigned)s < DIM) {
            const float4* sl = src + (size_t)s * (DIM * DIM / 4);
            if (v0ok) ld0 = sl[goff0];
            if (v1ok) ld1 = sl[goff1];
        }
    };
    auto swrite = [&](float* buf) {        // commit staged regs to LDS
        *(float4*)(buf + loff0) = ld0;
        if (i1 < NSTAGE) *(float4*)(buf + loff1) = ld1;
    };
    auto wtap = [&](const float* row, int c) -> float4 {
        float4 v0 = *(const float4*)(row + 4 * c);
        float4 v1 = *(const float4*)(row + 4 * c + 4);
        float4 v2 = *(const float4*)(row + 4 * c + 8);
        float f1 = v0.y, f2 = v0.z, f3 = v0.w;
        float f4_ = v1.x, f5 = v1.y, f6 = v1.z, f7 = v1.w;
        float f8 = v2.x, f9 = v2.y, f10 = v2.z;
        float4 o;
        o.x = wt.w[0]*f1 + wt.w[1]*f2 + wt.w[2]*f3 + wt.w[3]*f4_
            + wt.w[4]*f5 + wt.w[5]*f6 + wt.w[6]*f7;
        o.y = wt.w[0]*f2 + wt.w[1]*f3 + wt.w[2]*f4_ + wt.w[3]*f5
            + wt.w[4]*f6 + wt.w[5]*f7 + wt.w[6]*f8;
        o.z = wt.w[0]*f3 + wt.w[1]*f4_ + wt.w[2]*f5 + wt.w[3]*f6
            + wt.w[4]*f7 + wt.w[5]*f8 + wt.w[6]*f9;
        o.w = wt.w[0]*f4_ + wt.w[1]*f5 + wt.w[2]*f6 + wt.w[3]*f7
            + wt.w[4]*f8 + wt.w[5]*f9 + wt.w[6]*f10;
        return o;
    };
    auto wblur = [&](const float* ib, float* tb) {
        *(float4*)(tb + rw0 * TST + 4 * cw0) = wtap(ib + rw0 * IST, cw0);
        if (w1ok)
            *(float4*)(tb + rw1 * TST + 4 * cw1) = wtap(ib + rw1 * IST, cw1);
    };
    auto hblur = [&](const float* tb) -> float4 {
        float4 a = z4;
#pragma unroll
        for (int j = 0; j < 7; ++j)
            fma4(a, wt.w[j], *(const float4*)(tb + (g + j) * TST + 4 * cc));
        return a;
    };

    // ---- prologue: inL[0]=slice0 raw; tmpL[0]=slice0 blurred; inL[1]=slice1 ----
    sload(d0 - 3);
    swrite(inL);
    __syncthreads();
    sload(d0 - 2);
    wblur(inL, tmpL);
    swrite(inL + ISL);
    __syncthreads();

    // ---- main march: 1 barrier per step, all VGPR indices static ----
    for (int t = 0; t < NSTEP; ++t) {
        const int pb = t & 1;
        const float* inCur  = inL  + (pb ^ 1) * ISL;   // raw slice t+1
        float*       inNext = (float*)inL + pb * ISL;  // receives slice t+2
        const float* tmpCur = tmpL + pb * TSL;         // blurred slice t
        float*       tmpNxt = (float*)tmpL + (pb ^ 1) * TSL;

        if (t < NSTEP - 2) sload(d0 - 1 + t);          // issue slice t+2 loads
        float4 nw = hblur(tmpCur);                     // H-blur slice t
        r0 = r1; r1 = r2; r2 = r3; r3 = r4; r4 = r5; r5 = r6; r6 = nw;
        if (t >= 6) {                                  // D-blur + store
            float4 o = z4;
            fma4(o, wt.w[0], r0); fma4(o, wt.w[1], r1); fma4(o, wt.w[2], r2);
            fma4(o, wt.w[3], r3); fma4(o, wt.w[4], r4); fma4(o, wt.w[5], r5);
            fma4(o, wt.w[6], r6);
            dst[(size_t)(d0 + t - 6) * (DIM * DIM / 4) + obase] = o;
        }
        if (t < NSTEP - 1) wblur(inCur, tmpNxt);       // W-blur slice t+1
        if (t < NSTEP - 2) swrite(inNext);             // commit slice t+2
        __syncthreads();
    }
}

extern "C" void kernel_launch(void* const* d_in, const int* in_sizes, int n_in,
                              void* d_out, int out_size, void* d_ws, size_t ws_size,
                              hipStream_t stream) {
    const float* x = (const float*)d_in[0];
    float* out = (float*)d_out;
    const int total = out_size;                        // 2*2*160^3

    W7 wt;
    double s = 0.0;
    for (int i = 0; i < 7; ++i) {
        double v = exp(-((i - 3) * (i - 3)) / 8.0);
        wt.w[i] = (float)v;
        s += v;
    }
    for (int i = 0; i < 7; ++i) wt.w[i] = (float)(wt.w[i] / s);

    const int nc = total / (DIM * DIM * DIM);          // 4
    const int grid = nc * (DIM / HT) * 2 * (DIM / CHUNK);  // 4*10*2*20 = 1600
    blur3d_fused<<<grid, THREADS, 0, stream>>>(
        (const float4*)x, (float4*)out, wt);
}

// Round 7
// 76.206 us; speedup vs baseline: 2.0323x; 1.1168x over previous
//
#include <hip/hip_runtime.h>
#include <math.h>

#define DIM 160
#define SL4 (DIM * DIM / 4)    // 6400 float4 per slice
#define CH 16                  // output h-rows per marching thread
#define DPB 8                  // d-slices per WH block (8*40 = 320 threads)
#define CHUNK 20               // d-slices per D-march thread
#define WHTHREADS (DPB * 40)

struct W7 { float w[7]; };

__device__ __forceinline__ void fma4(float4& a, float w, const float4& v) {
    a.x += w * v.x; a.y += w * v.y; a.z += w * v.z; a.w += w * v.w;
}

// ---- Fused W+H blur, barrier-free register march along H: x -> ws ----
__global__ __launch_bounds__(WHTHREADS) void blur_wh_march(
    const float4* __restrict__ in, float4* __restrict__ out, W7 wt) {
    const int hchunks = DIM / CH;                   // 10
    const int dgroups = DIM / DPB;                  // 20
    int b  = blockIdx.x;
    int hc = b % hchunks;                           // fastest: h-halo L2 locality
    int dg = (b / hchunks) % dgroups;
    int nc = b / (hchunks * dgroups);

    const int c  = threadIdx.x % 40;                // f4 column
    const int dl = threadIdx.x / 40;                // 0..7
    const int d  = dg * DPB + dl;
    const int h0 = hc * CH;

    const float4* sl  = in  + ((size_t)nc * DIM + d) * SL4;
    float4*       osl = out + ((size_t)nc * DIM + d) * SL4;

    const float4 z4 = make_float4(0.f, 0.f, 0.f, 0.f);
    float4 ring[7];
#pragma unroll
    for (int j = 0; j < 7; ++j) ring[j] = z4;

    const bool cl = (c >= 1), cr = (c <= 38);
    const float w0 = wt.w[0], w1 = wt.w[1], w2 = wt.w[2], w3 = wt.w[3],
                w4 = wt.w[4], w5 = wt.w[5], w6 = wt.w[6];

#pragma unroll
    for (int k = 0; k < CH + 6; ++k) {              // 22 fully-static steps
        const int hh = h0 + k - 3;                  // row being W-blurred
        float4 nw = z4;
        if ((unsigned)hh < DIM) {
            const float4* row = sl + hh * 40;
            float4 l = cl ? row[c - 1] : z4;
            float4 m = row[c];
            float4 r = cr ? row[c + 1] : z4;
            float f1 = l.y, f2 = l.z, f3 = l.w;
            float f4_ = m.x, f5 = m.y, f6 = m.z, f7 = m.w;
            float f8 = r.x, f9 = r.y, f10 = r.z;
            nw.x = w0*f1 + w1*f2 + w2*f3 + w3*f4_ + w4*f5 + w5*f6 + w6*f7;
            nw.y = w0*f2 + w1*f3 + w2*f4_ + w3*f5 + w4*f6 + w5*f7 + w6*f8;
            nw.z = w0*f3 + w1*f4_ + w2*f5 + w3*f6 + w4*f7 + w5*f8 + w6*f9;
            nw.w = w0*f4_ + w1*f5 + w2*f6 + w3*f7 + w4*f8 + w5*f9 + w6*f10;
        }
        ring[k % 7] = nw;
        if (k >= 6) {
            float4 o = z4;
#pragma unroll
            for (int j = 0; j < 7; ++j)
                fma4(o, wt.w[j], ring[(k + 1 + j) % 7]);
            osl[(h0 + k - 6) * 40 + c] = o;
        }
    }
}

// ---- D blur, register sliding window (proven 5.8 TB/s): ws -> out ----
__global__ __launch_bounds__(256) void blur_dm(const float4* __restrict__ in,
                                               float4* __restrict__ out, W7 wt) {
    const int sblocks = SL4 / 256;               // 25
    const int nchunks = DIM / CHUNK;             // 8
    int b     = blockIdx.x;
    int sblk  = b % sblocks;
    int chunk = (b / sblocks) % nchunks;
    int ch    = b / (sblocks * nchunks);
    int s4    = sblk * 256 + threadIdx.x;
    int d0    = chunk * CHUNK;
    const size_t base = (size_t)ch * DIM * SL4;

    const float4 z4 = make_float4(0.f, 0.f, 0.f, 0.f);
    float4 win[7];
#pragma unroll
    for (int j = 0; j < 6; ++j) {
        int dd = d0 - 3 + j;
        win[j] = (dd >= 0 && dd < DIM) ? in[base + (size_t)dd * SL4 + s4] : z4;
    }
#pragma unroll
    for (int k = 0; k < CHUNK; ++k) {
        int dd = d0 + k + 3;
        win[(k + 6) % 7] = (dd < DIM) ? in[base + (size_t)dd * SL4 + s4] : z4;
        float4 acc = z4;
#pragma unroll
        for (int j = 0; j < 7; ++j)
            fma4(acc, wt.w[j], win[(k + j) % 7]);
        out[base + (size_t)(d0 + k) * SL4 + s4] = acc;
    }
}

// ---- Fallback: direct 343-tap (only if ws too small) ----
__global__ void blur3d_naive(const float* __restrict__ in, float* __restrict__ out,
                             W7 wt, int total) {
    int idx = blockIdx.x * blockDim.x + threadIdx.x;
    if (idx >= total) return;
    int w = idx % DIM;
    int h = (idx / DIM) % DIM;
    int d = (idx / (DIM * DIM)) % DIM;
    const float* base = in + (idx - w - h * DIM - d * DIM * DIM);
    float acc = 0.f;
    for (int a = 0; a < 7; ++a) {
        int dd = d + a - 3;
        if (dd < 0 || dd >= DIM) continue;
        for (int bb = 0; bb < 7; ++bb) {
            int hh = h + bb - 3;
            if (hh < 0 || hh >= DIM) continue;
            float wab = wt.w[a] * wt.w[bb];
            for (int cx = 0; cx < 7; ++cx) {
                int ww = w + cx - 3;
                if (ww < 0 || ww >= DIM) continue;
                acc += wab * wt.w[cx] * base[(dd * DIM + hh) * DIM + ww];
            }
        }
    }
    out[idx] = acc;
}

extern "C" void kernel_launch(void* const* d_in, const int* in_sizes, int n_in,
                              void* d_out, int out_size, void* d_ws, size_t ws_size,
                              hipStream_t stream) {
    const float* x = (const float*)d_in[0];
    float* out = (float*)d_out;
    const int total = out_size;                    // 2*2*160^3

    W7 wt;
    double s = 0.0;
    for (int i = 0; i < 7; ++i) {
        double v = exp(-((i - 3) * (i - 3)) / 8.0);
        wt.w[i] = (float)v;
        s += v;
    }
    for (int i = 0; i < 7; ++i) wt.w[i] = (float)(wt.w[i] / s);

    if (ws_size >= (size_t)total * sizeof(float)) {
        float* tmp = (float*)d_ws;
        const int nc = total / (DIM * DIM * DIM);                 // 4
        const int gridWH = nc * (DIM / DPB) * (DIM / CH);         // 4*20*10 = 800
        blur_wh_march<<<gridWH, WHTHREADS, 0, stream>>>(
            (const float4*)x, (float4*)tmp, wt);
        const int gridD = nc * (DIM / CHUNK) * (SL4 / 256);       // 800
        blur_dm<<<gridD, 256, 0, stream>>>(
            (const float4*)tmp, (float4*)out, wt);
    } else {
        blur3d_naive<<<(total + 255) / 256, 256, 0, stream>>>(x, out, wt, total);
    }
}